// Round 6
// baseline (316.032 us; speedup 1.0000x reference)
//
#include <hip/hip_runtime.h>

// ---------------------------------------------------------------------------
// SimpleBiquadEQ: 10-band peaking-EQ cascade (IIR) over [32,2,262144] fp32.
// Round 8 (resubmit; round-5 bench was a container-acquisition failure):
//  - pass_eq<false>: r3's proven lean shape (4096 single-wave WGs, one 16 KB
//    tile, global_load_lds). Computes biquad coefs IN-WAVE (lane<10 +
//    v_readlane -> SGPRs). Writes per-chunk end-state T (transposed layout).
//  - scan_mid (64 WGs x 256 thr): builds A + powers in LDS, then
//    fold (8 Horner matvecs per group, 2 groups/thread, coalesced T reads)
//    -> 9-step Kogge-Stone in LDS (SoA float2, conflict-free)
//    -> rewalk writes per-chunk INCLUSIVE prefixes back into T in place.
//    256 threads => no 128-VGPR cap (the r5 spill trap); live set ~110.
//  - pass_eq<true>: lean pass again; state init = read T[chunk-1] (5 float4).
//    No sbuf, no shuffles, no matrices.
//  - Launches 5 -> 3 (setup eliminated; gbuf/sbuf eliminated; ws = T only).
// ---------------------------------------------------------------------------

#define B_   32
#define C_   2
#define S_   262144
#define NB   10
#define SEQ  64

#define F_LCH   64          // samples per chunk
#define F_PCH   4096        // chunks per sequence
#define F_G     8           // chunks per scan group
#define F_GRP   512         // groups per sequence

// T layout (float4 units): plane(seq,j,i) = ((seq*8 + j)*5 + i)*512, + g
// where chunk = 8*g + j.  Per seq: 40 planes x 512 float4.

// ===========================================================================
// shared matvec helper (M col-major in LDS: M[c*20+r]); acc += M*v
// ===========================================================================
__device__ __forceinline__ void matvec_acc(const float* M,
                                           const float* v, float* acc) {
  #pragma unroll
  for (int c = 0; c < 20; c++) {
    float vc = v[c];
    const float4* col = (const float4*)&M[c*20];
    float4 c0 = col[0], c1 = col[1], c2 = col[2], c3 = col[3], c4 = col[4];
    acc[0]  = fmaf(c0.x, vc, acc[0]);  acc[1]  = fmaf(c0.y, vc, acc[1]);
    acc[2]  = fmaf(c0.z, vc, acc[2]);  acc[3]  = fmaf(c0.w, vc, acc[3]);
    acc[4]  = fmaf(c1.x, vc, acc[4]);  acc[5]  = fmaf(c1.y, vc, acc[5]);
    acc[6]  = fmaf(c1.z, vc, acc[6]);  acc[7]  = fmaf(c1.w, vc, acc[7]);
    acc[8]  = fmaf(c2.x, vc, acc[8]);  acc[9]  = fmaf(c2.y, vc, acc[9]);
    acc[10] = fmaf(c2.z, vc, acc[10]); acc[11] = fmaf(c2.w, vc, acc[11]);
    acc[12] = fmaf(c3.x, vc, acc[12]); acc[13] = fmaf(c3.y, vc, acc[13]);
    acc[14] = fmaf(c3.z, vc, acc[14]); acc[15] = fmaf(c3.w, vc, acc[15]);
    acc[16] = fmaf(c4.x, vc, acc[16]); acc[17] = fmaf(c4.y, vc, acc[17]);
    acc[18] = fmaf(c4.z, vc, acc[18]); acc[19] = fmaf(c4.w, vc, acc[19]);
  }
}

// per-band RBJ peaking coefficients (normalized, na1 = -a1, na2 = -a2)
__device__ __forceinline__ void peak_coefs(float f, float g, float Q,
                                           float& c0, float& c1, float& c2,
                                           float& c3, float& c4) {
  float w0 = 6.28318530717958648f * f / 44100.0f;
  float sw = sinf(w0), cw = cosf(w0);
  float alpha = sw / (2.0f * Q);
  float A = expf(g * 0.05756462732485114f);   // 10^(g/40)
  float aA = alpha * A, adA = alpha / A;
  float inv = 1.0f / (1.0f + adA);
  c0 = (1.0f + aA) * inv;
  c1 = -2.0f * cw * inv;
  c2 = (1.0f - aA) * inv;
  c3 = 2.0f * cw * inv;      // -a1
  c4 = -(1.0f - adA) * inv;  // -a2
}

// ===========================================================================
// passes: 1 wave per wg, one 16 KB tile, coefs computed in-wave -> SGPRs.
// ===========================================================================
template <bool WRITE_OUT>
__global__ __launch_bounds__(64) void pass_eq(
    const float* __restrict__ x,
    const float* __restrict__ freqs, const float* __restrict__ gains,
    const float* __restrict__ qs,
    float* __restrict__ t, float* __restrict__ out) {
  __shared__ __align__(16) float4 smem[1024];   // 16 KB tile
  const int seq = blockIdx.y;
  const int b = seq >> 1;
  const int lane = threadIdx.x;
  const int tile = blockIdx.x;               // 0..63
  const int chunk = tile * F_LCH + lane;     // seq-local chunk id
  const float* xseq = x + (size_t)seq * S_;

  // ---- stage tile: pre-swizzled global source, linear LDS dest ----
  const float4* gx = (const float4*)(xseq + (size_t)tile * 4096);
  #pragma unroll
  for (int it = 0; it < 16; it++) {
    const int f = it * 64 + lane;
    const int c = f >> 4;
    const int gi = (c << 4) | ((f & 15) ^ (c & 15));
    __builtin_amdgcn_global_load_lds(
        (const __attribute__((address_space(1))) void*)(gx + gi),
        (__attribute__((address_space(3))) void*)(smem + it * 64),
        16, 0, 0);
  }
  // ---- edge samples (x[-1], x[-2] of the tile) ----
  float2 pe = make_float2(0.f, 0.f);
  if (tile > 0) pe = *((const float2*)gx - 1);   // broadcast
  // ---- <true>: prefix state = T[chunk-1] (inclusive prefix of c-1) ----
  float4 st4[5];
  if constexpr (WRITE_OUT) {
    const int cm1 = (chunk > 0) ? chunk - 1 : 0;
    const int jj = cm1 & 7, gg = cm1 >> 3;
    const float4* sv = (const float4*)t + ((size_t)seq * 8 + jj) * 5 * 512 + gg;
    #pragma unroll
    for (int i = 0; i < 5; i++) st4[i] = sv[i * 512];
  }
  // ---- coefs in-wave: lane k<10 computes band k; readlane -> SGPRs ----
  float cc0 = 0.f, cc1 = 0.f, cc2 = 0.f, cc3 = 0.f, cc4 = 0.f;
  if (lane < NB) {
    int idx = b * NB + lane;
    peak_coefs(freqs[idx], gains[idx], qs[idx], cc0, cc1, cc2, cc3, cc4);
  }
  float b0[NB], b1[NB], b2[NB], na1[NB], na2[NB];
  #pragma unroll
  for (int k = 0; k < NB; k++) {
    b0[k]  = __uint_as_float(__builtin_amdgcn_readlane(__float_as_uint(cc0), k));
    b1[k]  = __uint_as_float(__builtin_amdgcn_readlane(__float_as_uint(cc1), k));
    b2[k]  = __uint_as_float(__builtin_amdgcn_readlane(__float_as_uint(cc2), k));
    na1[k] = __uint_as_float(__builtin_amdgcn_readlane(__float_as_uint(cc3), k));
    na2[k] = __uint_as_float(__builtin_amdgcn_readlane(__float_as_uint(cc4), k));
  }

  asm volatile("s_waitcnt vmcnt(0) lgkmcnt(0)" ::: "memory");
  __builtin_amdgcn_sched_barrier(0);

  // ---- init filter state ----
  float p[NB], q_[NB];
  if constexpr (WRITE_OUT) {
    const bool z = (chunk == 0);
    #pragma unroll
    for (int i = 0; i < 5; i++) {
      float4 a = st4[i];
      p[2*i]   = z ? 0.f : a.x;  q_[2*i]   = z ? 0.f : a.y;
      p[2*i+1] = z ? 0.f : a.z;  q_[2*i+1] = z ? 0.f : a.w;
    }
  } else {
    #pragma unroll
    for (int k = 0; k < NB; k++) { p[k] = 0.0f; q_[k] = 0.0f; }
  }
  // ---- x1/x2 init from neighbor chunk in LDS ----
  float x1, x2;
  if (lane == 0) {
    x1 = pe.y; x2 = pe.x;            // zeros when tile==0
  } else {
    float4 pv = smem[(lane-1)*16 + (15 ^ ((lane-1) & 15))];
    x2 = pv.z; x1 = pv.w;
  }
  // ---- filter: my chunk = lane, 16 float4 from LDS ----
  #pragma unroll 2
  for (int qq = 0; qq < 16; qq++) {
    const int slot = lane*16 + (qq ^ (lane & 15));
    float4 xv = smem[slot];
    float xin[4] = {xv.x, xv.y, xv.z, xv.w};
    float o[4];
    #pragma unroll
    for (int j = 0; j < 4; j++) {
      float u = xin[j], u1 = x1, u2 = x2;
      x2 = x1; x1 = xin[j];
      #pragma unroll
      for (int k = 0; k < NB; k++) {
        float v = fmaf(b0[k], u,
                  fmaf(b1[k], u1,
                  fmaf(b2[k], u2,
                  fmaf(na1[k], p[k], na2[k] * q_[k]))));
        u1 = p[k]; u2 = q_[k];
        q_[k] = p[k]; p[k] = v;
        u = v;
      }
      o[j] = u;
    }
    if (WRITE_OUT) smem[slot] = make_float4(o[0], o[1], o[2], o[3]);
  }
  if constexpr (WRITE_OUT) {
    asm volatile("" ::: "memory");   // keep ds_writes before store-phase reads
    float4* gy = (float4*)(out + (size_t)seq * S_ + (size_t)tile * 4096);
    #pragma unroll 4
    for (int it = 0; it < 16; it++) {
      int f = it * 64 + lane;
      int c = f >> 4, q = f & 15;
      gy[f] = smem[c*16 + (q ^ (c & 15))];
    }
  } else {
    // ---- T write (transposed planes) ----
    const int jj = chunk & 7, gg = chunk >> 3;
    float4* td = (float4*)t + ((size_t)seq * 8 + jj) * 5 * 512 + gg;
    td[0]    = make_float4(p[0], q_[0], p[1], q_[1]);
    td[512]  = make_float4(p[2], q_[2], p[3], q_[3]);
    td[1024] = make_float4(p[4], q_[4], p[5], q_[5]);
    td[1536] = make_float4(p[6], q_[6], p[7], q_[7]);
    td[2048] = make_float4(p[8], q_[8], p[9], q_[9]);
  }
}

// ===========================================================================
// scan_mid: one 256-thread WG per sequence.
//   prologue: coefs -> A -> powers (A^64 col-major -> Msh; A^(512*2^s)
//             col-major -> Ks[s], s=0..8), all in LDS.
//   fold:     per group g (2 per thread): s = Horner_{j=0..7}(A^64, T_j);
//             h2[g] = s.
//   KS:       9 steps over 512 group totals (SoA float2 LDS, conflict-free).
//   rewalk:   s = h2[g-1] (exclusive); for j: s = A^64*s + T_j; T_j = s
//             (T becomes per-chunk INCLUSIVE prefix, in place).
// ===========================================================================
__global__ __launch_bounds__(256) void scan_mid(
    float* __restrict__ t,
    const float* __restrict__ freqs, const float* __restrict__ gains,
    const float* __restrict__ qs) {
  __shared__ float2 h2[10 * 512];                 // 40 KB, h2[r2*512+g]
  __shared__ __align__(16) float Msh[400];        // A^64 col-major
  __shared__ __align__(16) float Ks[9][400];      // KS matrices col-major
  __shared__ float bufA[400], bufB[400];
  __shared__ float cfs[NB * 5];
  const int seq = blockIdx.x, b = seq >> 1, tid = threadIdx.x;

  // ---- coefs ----
  for (int e = tid; e < 400; e += 256) bufA[e] = 0.0f;
  if (tid < NB) {
    int idx = b * NB + tid;
    float c0, c1, c2, c3, c4;
    peak_coefs(freqs[idx], gains[idx], qs[idx], c0, c1, c2, c3, c4);
    cfs[tid*5+0] = c0; cfs[tid*5+1] = c1; cfs[tid*5+2] = c2;
    cfs[tid*5+3] = c3; cfs[tid*5+4] = c4;
  }
  __syncthreads();
  // ---- build A (rows p_k at 2k, q_k at 2k+1); thread tid<20 owns column ----
  if (tid < 20) {
    int c = tid;
    float rp = 0.0f;
    for (int k = 0; k < NB; k++) {
      float b0 = cfs[k*5+0], b1 = cfs[k*5+1], b2 = cfs[k*5+2];
      float na1 = cfs[k*5+3], na2 = cfs[k*5+4];
      float val = (k > 0) ? b0 * rp : 0.0f;
      if (k > 0) {
        if (c == 2*k-2) val += b1;
        if (c == 2*k-1) val += b2;
      }
      if (c == 2*k)   val += na1;
      if (c == 2*k+1) val += na2;
      bufA[2*k*20 + c] = val;
      rp = val;
      if (c == 2*k) bufA[(2*k+1)*20 + c] = 1.0f;
    }
  }
  __syncthreads();
  // ---- powers: cur = A^(2^j); save j=6 -> Msh, j=9..17 -> Ks[j-9] ----
  {
    float* cur = bufA;
    float* nxt = bufB;
    for (int j = 1; j <= 17; j++) {
      for (int e = tid; e < 400; e += 256) {
        int r = e / 20, c = e % 20;
        float acc = 0.0f;
        #pragma unroll
        for (int k = 0; k < 20; k++) acc = fmaf(cur[r*20+k], cur[k*20+c], acc);
        nxt[e] = acc;
      }
      __syncthreads();
      { float* t_ = cur; cur = nxt; nxt = t_; }
      float* dst = nullptr;
      if (j == 6) dst = Msh;
      else if (j >= 9) dst = Ks[j - 9];
      if (dst)
        for (int e = tid; e < 400; e += 256)
          dst[(e % 20) * 20 + e / 20] = cur[e];   // col-major
    }
  }
  __syncthreads();

  // ---- fold: 2 groups per thread, sequential ----
  const float4* tbase = (const float4*)t + (size_t)seq * 40 * 512;
  #pragma unroll 1
  for (int half = 0; half < 2; half++) {
    const int g = tid + half * 256;
    const float4* tb = tbase + g;
    float s[20];
    #pragma unroll
    for (int r = 0; r < 20; r++) s[r] = 0.0f;
    #pragma unroll 1
    for (int j = 0; j < F_G; j++) {
      float ns[20];
      #pragma unroll
      for (int i = 0; i < 5; i++) {
        float4 a = tb[(j*5 + i) * 512];
        ns[4*i] = a.x; ns[4*i+1] = a.y; ns[4*i+2] = a.z; ns[4*i+3] = a.w;
      }
      matvec_acc(Msh, s, ns);
      #pragma unroll
      for (int r = 0; r < 20; r++) s[r] = ns[r];
    }
    #pragma unroll
    for (int r2 = 0; r2 < 10; r2++)
      h2[r2*512 + g] = make_float2(s[2*r2], s[2*r2+1]);
  }
  __syncthreads();

  // ---- Kogge-Stone over 512 group totals (2 entries per thread) ----
  #pragma unroll 1
  for (int st = 0; st < 9; st++) {
    const int d = 1 << st;
    const float* K = Ks[st];
    const int iA = tid, iB = tid + 256;
    float oA[20], nA[20], oB[20], nB[20];
    const bool doA = (iA >= d);
    #pragma unroll
    for (int r2 = 0; r2 < 10; r2++) {
      float2 v = h2[r2*512 + iA]; oA[2*r2] = v.x; oA[2*r2+1] = v.y;
    }
    if (doA) {
      #pragma unroll
      for (int r2 = 0; r2 < 10; r2++) {
        float2 v = h2[r2*512 + iA - d]; nA[2*r2] = v.x; nA[2*r2+1] = v.y;
      }
    }
    #pragma unroll
    for (int r2 = 0; r2 < 10; r2++) {
      float2 v = h2[r2*512 + iB]; oB[2*r2] = v.x; oB[2*r2+1] = v.y;
    }
    #pragma unroll
    for (int r2 = 0; r2 < 10; r2++) {
      float2 v = h2[r2*512 + iB - d]; nB[2*r2] = v.x; nB[2*r2+1] = v.y;
    }
    __syncthreads();               // all reads done before any write
    if (doA) {
      matvec_acc(K, nA, oA);
      #pragma unroll
      for (int r2 = 0; r2 < 10; r2++)
        h2[r2*512 + iA] = make_float2(oA[2*r2], oA[2*r2+1]);
    }
    matvec_acc(K, nB, oB);         // iB >= 256 >= d always
    #pragma unroll
    for (int r2 = 0; r2 < 10; r2++)
      h2[r2*512 + iB] = make_float2(oB[2*r2], oB[2*r2+1]);
    __syncthreads();               // writes done before next step's reads
  }

  // ---- rewalk: exclusive prefix from h2[g-1]; T_j := inclusive prefix ----
  #pragma unroll 1
  for (int half = 0; half < 2; half++) {
    const int g = tid + half * 256;
    float s[20];
    if (g > 0) {
      #pragma unroll
      for (int r2 = 0; r2 < 10; r2++) {
        float2 v = h2[r2*512 + g - 1]; s[2*r2] = v.x; s[2*r2+1] = v.y;
      }
    } else {
      #pragma unroll
      for (int r = 0; r < 20; r++) s[r] = 0.0f;
    }
    float4* tw = (float4*)t + (size_t)seq * 40 * 512 + g;
    #pragma unroll 1
    for (int j = 0; j < F_G; j++) {
      float ns[20];
      #pragma unroll
      for (int i = 0; i < 5; i++) {
        float4 a = tw[(j*5 + i) * 512];
        ns[4*i] = a.x; ns[4*i+1] = a.y; ns[4*i+2] = a.z; ns[4*i+3] = a.w;
      }
      matvec_acc(Msh, s, ns);
      #pragma unroll
      for (int r = 0; r < 20; r++) s[r] = ns[r];
      float4* wp = tw + (size_t)(j*5) * 512;
      wp[0]    = make_float4(s[0],  s[1],  s[2],  s[3]);
      wp[512]  = make_float4(s[4],  s[5],  s[6],  s[7]);
      wp[1024] = make_float4(s[8],  s[9],  s[10], s[11]);
      wp[1536] = make_float4(s[12], s[13], s[14], s[15]);
      wp[2048] = make_float4(s[16], s[17], s[18], s[19]);
    }
  }
}

// ===========================================================================
extern "C" void kernel_launch(void* const* d_in, const int* in_sizes, int n_in,
                              void* d_out, int out_size, void* d_ws, size_t ws_size,
                              hipStream_t stream) {
  const float* audio = (const float*)d_in[0];
  const float* freqs = (const float*)d_in[1];
  const float* gains = (const float*)d_in[2];
  const float* qs    = (const float*)d_in[3];
  float* out = (float*)d_out;
  float* t   = (float*)d_ws;   // 21 MB chunk-state tensor (only ws user)

  hipLaunchKernelGGL((pass_eq<false>), dim3(F_PCH / F_LCH, SEQ), dim3(64), 0,
                     stream, audio, freqs, gains, qs, t, (float*)nullptr);
  hipLaunchKernelGGL(scan_mid, dim3(SEQ), dim3(256), 0, stream,
                     t, freqs, gains, qs);
  hipLaunchKernelGGL((pass_eq<true>), dim3(F_PCH / F_LCH, SEQ), dim3(64), 0,
                     stream, audio, freqs, gains, qs, t, out);
}